// Round 9
// baseline (149.461 us; speedup 1.0000x reference)
//
#include <hip/hip_runtime.h>

#define BINS 16
#define OUT_DIM 64
#define NB 64
#define NCH 3
#define NPIX (512 * 512)                 // pixels per (b,c) plane, = 2^18
#define BATCH_PIX (NCH * NPIX)           // 786432 pixels per batch
#define THREADS 512
#define BLOCKS_PER_BATCH 32
#define NBLOCKS (NB * BLOCKS_PER_BATCH)  // 2048 = 4 blocks/CU x 8 waves = 32 waves/CU, 1 round
#define PX_PER_BLOCK (BATCH_PIX / BLOCKS_PER_BATCH)   // 24576 (< 2^16: u16 counts)
#define VEC_ITERS (PX_PER_BLOCK / 4 / THREADS)        // 12 f32x4 per thread
#define IN_DIM (NCH * BINS)              // 48
#define PACK_W (IN_DIM / 2)              // 24 u32 per block (two u16 counts each)

typedef float f32x4 __attribute__((ext_vector_type(4)));

// Single fused dispatch (plus a 256 B ticket-reset memset in the same graph).
// Block (b,k) = (blockIdx>>5, blockIdx&31) histograms pixel slice
// [blockIdx*24576, +24576) of batch b (channel c = in_batch_px >> 18).
// LDS hist: [3ch][16bins][64 lane replicas] (addr = (c*16+bin)*64+lane ->
// bank = lane%32: free 2-way aliasing, zero same-address contention).
// Publish: AGENT-scoped atomic stores; __syncthreads (drains vmcnt);
// ticket fetch_add ACQ_REL on done[b] (zeroed by the preceding memset every
// call -> t==31 is provably the LAST block of batch b; R6/R7 failed because a
// poisoned counter makes the residue-31 holder an EARLY arriver, not last).
// Winner: acquire fence, reduce 32 partials -> feat[48] -> FC + ReLU.
__global__ __launch_bounds__(THREADS, 8) void fused_kernel(const float* __restrict__ x,
                                                           const float* __restrict__ fc_w,
                                                           const float* __restrict__ fc_b,
                                                           float* __restrict__ out,
                                                           unsigned int* __restrict__ ws) {
    unsigned int* partials = ws;                       // [NBLOCKS][PACK_W]
    unsigned int* done     = ws + NBLOCKS * PACK_W;    // [NB], zeroed each call

    __shared__ unsigned int lh[NCH * BINS * 64];       // 12 KB
    __shared__ float feat[IN_DIM];
    __shared__ unsigned int win;

    const int tid  = threadIdx.x;
    const int lane = tid & 63;
    const int b    = blockIdx.x >> 5;
    const int k    = blockIdx.x & 31;

    for (int i = tid; i < NCH * BINS * 64; i += THREADS) lh[i] = 0u;
    __syncthreads();

    const f32x4* __restrict__ src = (const f32x4*)(x + (size_t)blockIdx.x * PX_PER_BLOCK);
    const int base_px = k * PX_PER_BLOCK;              // offset within batch

    #pragma unroll
    for (int it = 0; it < VEC_ITERS; ++it) {
        const int vidx = it * THREADS + tid;
        f32x4 v = src[vidx];
        const int c = (base_px + (vidx << 2)) >> 18;   // channel of these 4 px
        const int h0 = c << 10;                        // c * 16*64
        // x in [0,1): (int)(x*16.0f) == floor(x*16) exactly (mul by 2^4 exact).
        // min(15,.) guards an exact-1.0 input from an OOB LDS write.
        int i0 = min(BINS - 1, (int)(v.x * 16.0f));
        int i1 = min(BINS - 1, (int)(v.y * 16.0f));
        int i2 = min(BINS - 1, (int)(v.z * 16.0f));
        int i3 = min(BINS - 1, (int)(v.w * 16.0f));
        atomicAdd(&lh[h0 + i0 * 64 + lane], 1u);
        atomicAdd(&lh[h0 + i1 * 64 + lane], 1u);
        atomicAdd(&lh[h0 + i2 * 64 + lane], 1u);
        atomicAdd(&lh[h0 + i3 * 64 + lane], 1u);
    }
    __syncthreads();

    // Pack feature pair (2t, 2t+1) into one u32 (counts <= 24576 < 2^16);
    // AGENT-scoped (coherent) store.
    if (tid < PACK_W) {
        unsigned int s0 = 0, s1 = 0;
        #pragma unroll
        for (int r = 0; r < 64; ++r) {
            s0 += lh[(2 * tid)     * 64 + r];
            s1 += lh[(2 * tid + 1) * 64 + r];
        }
        __hip_atomic_store(&partials[(size_t)blockIdx.x * PACK_W + tid],
                           s0 | (s1 << 16), __ATOMIC_RELEASE, __HIP_MEMORY_SCOPE_AGENT);
    }
    __syncthreads();   // block-wide: all partial stores drained before the ticket

    if (tid == 0) {
        unsigned int t = __hip_atomic_fetch_add(&done[b], 1u,
                                                __ATOMIC_ACQ_REL, __HIP_MEMORY_SCOPE_AGENT);
        win = (t == BLOCKS_PER_BATCH - 1) ? 1u : 0u;   // done[b]==0 at call start -> last
    }
    __syncthreads();
    if (!win) return;

    __builtin_amdgcn_fence(__ATOMIC_ACQUIRE, "agent");

    // ---- last block of batch b: reduce 32 partials -> feat[48] ----
    if (tid < IN_DIM) {
        const int w = tid >> 1, hi = tid & 1;
        unsigned int s = 0;
        #pragma unroll
        for (int blk = 0; blk < BLOCKS_PER_BATCH; ++blk) {
            unsigned int p = __hip_atomic_load(
                &partials[(size_t)(b * BLOCKS_PER_BATCH + blk) * PACK_W + w],
                __ATOMIC_RELAXED, __HIP_MEMORY_SCOPE_AGENT);
            s += hi ? (p >> 16) : (p & 0xFFFFu);
        }
        feat[tid] = (float)s * (1.0f / (float)NPIX);   // exact pow2 divide
    }
    __syncthreads();

    // ---- FC + ReLU for batch b ----
    if (tid < OUT_DIM) {
        float s = fc_b[tid];
        #pragma unroll
        for (int j = 0; j < IN_DIM; ++j)
            s = fmaf(feat[j], fc_w[tid * IN_DIM + j], s);
        out[b * OUT_DIM + tid] = fmaxf(s, 0.0f);
    }
}

extern "C" void kernel_launch(void* const* d_in, const int* in_sizes, int n_in,
                              void* d_out, int out_size, void* d_ws, size_t ws_size,
                              hipStream_t stream) {
    const float* x    = (const float*)d_in[0];
    const float* fc_w = (const float*)d_in[1];
    const float* fc_b = (const float*)d_in[2];
    float* out = (float*)d_out;
    unsigned int* ws = (unsigned int*)d_ws;  // [2048][24] partials + [64] tickets

    unsigned int* done = ws + NBLOCKS * PACK_W;
    (void)hipMemsetAsync(done, 0, NB * sizeof(unsigned int), stream);  // known-zero tickets
    fused_kernel<<<NBLOCKS, THREADS, 0, stream>>>(x, fc_w, fc_b, out, ws);
}

// Round 10
// 38.757 us; speedup vs baseline: 3.8563x; 3.8563x over previous
//
#include <hip/hip_runtime.h>

#define BINS 16
#define OUT_DIM 64
#define NB 64
#define NCH 3
#define NPIX (512 * 512)                  // pixels per (b,c) plane, = 2^18
#define BATCH_PIX (NCH * NPIX)            // 786432 pixels per batch
#define THREADS 256
#define SLICES_PER_BATCH 32
#define NBLOCKS (NB * SLICES_PER_BATCH)   // 2048 = exactly 8 blocks/CU, single round
#define PX_PER_BLOCK (BATCH_PIX / SLICES_PER_BATCH)   // 24576 pixels per block
#define VEC_ITERS (PX_PER_BLOCK / 4 / THREADS)        // 24 f32x4 per thread
#define IN_DIM (NCH * BINS)               // 48

typedef float f32x4 __attribute__((ext_vector_type(4)));

// Two plain dispatches (R9 lesson: agent-scope atomics trigger per-XCD L2
// writeback/invalidate traffic that costs 100+ us; dispatch-boundary
// visibility is free and correct). Kernel 1: 2048 blocks = exactly 8/CU
// (one round, no half-occupancy tail — R2 had 3072 blocks = 1.5 rounds).
// Block i histograms contiguous pixels [i*24576, +24576): batch b = i>>5,
// channel c = in_batch_px >> 18 (slices align to batch boundaries).
// LDS hist [3ch][16bins][64 lane replicas]: addr = (c*16+bin)*64+lane ->
// bank = lane%32: free 2-way aliasing, zero same-address contention.
// Non-atomic partial store of 48 counts per block.
__global__ __launch_bounds__(THREADS, 8) void hist_kernel(const float* __restrict__ x,
                                                          unsigned int* __restrict__ partials) {
    __shared__ unsigned int lh[NCH * BINS * 64];   // 12 KB -> 8 blocks/CU
    for (int i = threadIdx.x; i < NCH * BINS * 64; i += THREADS) lh[i] = 0u;
    __syncthreads();

    const int tid  = threadIdx.x;
    const int lane = tid & 63;
    const f32x4* __restrict__ src = (const f32x4*)(x + (size_t)blockIdx.x * PX_PER_BLOCK);
    const int base_px = (blockIdx.x & (SLICES_PER_BATCH - 1)) * PX_PER_BLOCK;

    #pragma unroll 4
    for (int it = 0; it < VEC_ITERS; ++it) {
        const int vidx = it * THREADS + tid;
        f32x4 v = src[vidx];
        const int c  = (base_px + (vidx << 2)) >> 18;  // channel of these 4 px
        const int h0 = c << 10;                        // c * 16*64
        // x in [0,1): (int)(x*16.0f) == floor(x*16) exactly (mul by 2^4 exact).
        // min(15,.) guards an exact-1.0 input from an OOB LDS write.
        int i0 = min(BINS - 1, (int)(v.x * 16.0f));
        int i1 = min(BINS - 1, (int)(v.y * 16.0f));
        int i2 = min(BINS - 1, (int)(v.z * 16.0f));
        int i3 = min(BINS - 1, (int)(v.w * 16.0f));
        atomicAdd(&lh[h0 + i0 * 64 + lane], 1u);
        atomicAdd(&lh[h0 + i1 * 64 + lane], 1u);
        atomicAdd(&lh[h0 + i2 * 64 + lane], 1u);
        atomicAdd(&lh[h0 + i3 * 64 + lane], 1u);
    }
    __syncthreads();

    // 48 threads: j = c*16 + bin; sum the 64 lane replicas; plain store.
    if (tid < IN_DIM) {
        unsigned int s = 0;
        #pragma unroll
        for (int k = 0; k < 64; ++k) s += lh[tid * 64 + k];
        partials[(size_t)blockIdx.x * IN_DIM + tid] = s;
    }
}

// Kernel 2: one block per batch b. partials[b*32 .. b*32+32)[48] -> feat[48]
// (counts/NPIX, exact pow2 divide) -> FC(48->64) + ReLU.
__global__ __launch_bounds__(256) void fc_kernel(const unsigned int* __restrict__ partials,
                                                 const float* __restrict__ fc_w,
                                                 const float* __restrict__ fc_b,
                                                 float* __restrict__ out) {
    __shared__ unsigned int tmp[SLICES_PER_BATCH * IN_DIM];  // 1536
    __shared__ float feat[IN_DIM];
    const int b = blockIdx.x;
    const int tid = threadIdx.x;

    const unsigned int* src = partials + (size_t)b * SLICES_PER_BATCH * IN_DIM;
    #pragma unroll
    for (int i = tid; i < SLICES_PER_BATCH * IN_DIM; i += 256) tmp[i] = src[i];
    __syncthreads();

    if (tid < IN_DIM) {
        unsigned int s = 0;
        #pragma unroll
        for (int blk = 0; blk < SLICES_PER_BATCH; ++blk)
            s += tmp[blk * IN_DIM + tid];
        feat[tid] = (float)s * (1.0f / (float)NPIX);   // exact pow2 divide
    }
    __syncthreads();

    if (tid < OUT_DIM) {
        float s = fc_b[tid];
        #pragma unroll
        for (int k = 0; k < IN_DIM; ++k)
            s = fmaf(feat[k], fc_w[tid * IN_DIM + k], s);
        out[b * OUT_DIM + tid] = fmaxf(s, 0.0f);
    }
}

extern "C" void kernel_launch(void* const* d_in, const int* in_sizes, int n_in,
                              void* d_out, int out_size, void* d_ws, size_t ws_size,
                              hipStream_t stream) {
    const float* x    = (const float*)d_in[0];
    const float* fc_w = (const float*)d_in[1];
    const float* fc_b = (const float*)d_in[2];
    float* out = (float*)d_out;
    unsigned int* partials = (unsigned int*)d_ws;  // [2048 blocks][48] = 393 KB

    hist_kernel<<<NBLOCKS, THREADS, 0, stream>>>(x, partials);
    fc_kernel<<<NB, 256, 0, stream>>>(partials, fc_w, fc_b, out);
}